// Round 6
// baseline (398.128 us; speedup 1.0000x reference)
//
#include <hip/hip_runtime.h>

typedef unsigned short u16;
typedef unsigned int   u32;
typedef __attribute__((ext_vector_type(8))) short short8;
typedef __attribute__((ext_vector_type(4))) float f32x4;

#define NN   2024
#define NB   128
#define HID  128
#define MTOT (NN*NB)      // 259072
#define TILE 128
#define TPB  8
#define BROWS (TILE*TPB)  // 1024
#define NPBLK (MTOT/BROWS) // 253

__device__ __forceinline__ float bflo(u32 w){ union{u32 u; float f;}c; c.u=w<<16;        return c.f; }
__device__ __forceinline__ float bfhi(u32 w){ union{u32 u; float f;}c; c.u=w&0xffff0000u; return c.f; }
__device__ __forceinline__ float bf2f(u16 h){ union{u32 u; float f;}c; c.u=((u32)h)<<16; return c.f; }
__device__ __forceinline__ u16 f2bf(float f){ union{float f; u32 u;}c; c.f=f; return (u16)((c.u+0x7fffu+((c.u>>16)&1u))>>16); }
__device__ __forceinline__ u32 cvtpk(float lo, float hi){
  u32 r; asm("v_cvt_pk_bf16_f32 %0, %1, %2" : "=v"(r) : "v"(lo), "v"(hi)); return r;
}
__device__ __forceinline__ f32x4 mfma16(short8 a, short8 b, f32x4 c){
  return __builtin_amdgcn_mfma_f32_16x16x32_bf16(a,b,c,0,0,0);
}
__device__ __forceinline__ void glds16(const void* g, void* l){
  __builtin_amdgcn_global_load_lds((const __attribute__((address_space(1))) void*)g,
                                   (__attribute__((address_space(3))) void*)l, 16, 0, 0);
}
__device__ __forceinline__ u32 agg1(u32 a, u32 b, u32 c, u32 d,
                                    float w0, float w1, float w2, float w3){
  float lo = w0*bflo(a); lo=fmaf(w1,bflo(b),lo); lo=fmaf(w2,bflo(c),lo); lo=fmaf(w3,bflo(d),lo);
  float hi = w0*bfhi(a); hi=fmaf(w1,bfhi(b),hi); hi=fmaf(w2,bfhi(c),hi); hi=fmaf(w3,bfhi(d),hi);
  return cvtpk(lo, hi);
}

// Persistent-block GNN layer (l>=2): out = LN(relu(h@W0 + agg(h)@W1 + b))*g + beta.
// 253 blocks x 512 thr, 1 block/CU. W in LDS once; 8 tiles of 128 rows;
// neighbor rows reg-prefetched one tile ahead; agg LDS double-buffered.
__global__ __launch_bounds__(512, 2)
void layerP_k(const u16* __restrict__ hin, const u16* __restrict__ Wt,
              const float* __restrict__ bias, const float* __restrict__ lng,
              const float* __restrict__ lnb, u16* __restrict__ hout)
{
  __shared__ __align__(16) char Wl[65536];      // [128 col][256k], 512B rows, XOR-swz
  __shared__ __align__(16) char Ag[2][32768];   // [128 row][128k], 256B rows, XOR-swz
  __shared__ __align__(16) float2 red[128][4];  // LN partials

  const int t  = threadIdx.x;
  const int l  = t & 63;
  const int wv = t >> 6;
  const int wr = wv & 1;          // 64-row half
  const int wc = wv >> 1;         // 32-col quarter
  const int cB = l & 15, rg = l >> 4;
  const int m0b = blockIdx.x * BROWS;
  const char* hb = (const char*)hin;

  // ---- stage W (both K-chunks, 64KB) once via global_load_lds ----
#pragma unroll
  for (int i = 0; i < 8; ++i){
    const int slot = wv*8 + i;                  // 64 slots x 1KB
    const int col  = slot*2 + (l >> 5);
    const u32 kb   = ((u32)((l & 31)*16)) ^ ((u32)((col & 7) << 4));
    glds16((const char*)Wt + (u32)col*512 + kb, Wl + (u32)slot*1024);
  }

  // ---- agg-build geometry: thread owns (row ar, 64B quarter aq) ----
  const int ar = t >> 2;
  const int aq = t & 3;
  const u32 qoff = (u32)aq * 64u;

  uint4 nb0[4], nb1[4], nb2[4], nb3[4];
  float wn0, wn1, wn2, wn3;
  auto prefetch = [&](int it2){
    const int rowg = m0b + it2*TILE + ar;
    const int nd = rowg % NN;
    const int v0 = (nd >= 45), v1 = (nd <= NN-46), v2 = (nd >= 1), v3 = (nd <= NN-2);
    const int cnt = v0+v1+v2+v3;
    const float inv = (cnt==4) ? 0.25f : ((cnt==3) ? (1.f/3.f) : 0.5f);
    wn0 = v0?inv:0.f; wn1 = v1?inv:0.f; wn2 = v2?inv:0.f; wn3 = v3?inv:0.f;
    const char* p0 = hb + (u32)(v0 ? rowg-45 : rowg)*256u + qoff;
    const char* p1 = hb + (u32)(v1 ? rowg+45 : rowg)*256u + qoff;
    const char* p2 = hb + (u32)(v2 ? rowg-1  : rowg)*256u + qoff;
    const char* p3 = hb + (u32)(v3 ? rowg+1  : rowg)*256u + qoff;
#pragma unroll
    for (int c = 0; c < 4; ++c){
      nb0[c] = *(const uint4*)(p0 + c*16);
      nb1[c] = *(const uint4*)(p1 + c*16);
      nb2[c] = *(const uint4*)(p2 + c*16);
      nb3[c] = *(const uint4*)(p3 + c*16);
    }
  };
  prefetch(0);

  // hoisted epilogue constants (cols fixed per thread across tiles)
  float bj[2], gj[2], btj[2];
#pragma unroll
  for (int j = 0; j < 2; ++j){
    const int col = 32*wc + 16*j + cB;
    bj[j] = bias[col]; gj[j] = lng[col]; btj[j] = lnb[col];
  }
  const u32 kswz = ((u32)(cB & 7)) << 4;
  const char* wp0 = Wl + (u32)(32*wc + cB)*512;
  const char* wp1 = Wl + (u32)(32*wc + 16 + cB)*512;

  __syncthreads();   // W resident

  for (int it = 0; it < TPB; ++it){
    const int m0t = m0b + it*TILE;
    char* agc = Ag[it & 1];

    // ---- build agg tile (consumes prefetched regs) ----
    {
      const float w0=wn0, w1=wn1, w2=wn2, w3=wn3;
      char* arow = agc + (u32)ar*256;
      const u32 sw = ((u32)(ar & 7)) << 4;
#pragma unroll
      for (int c = 0; c < 4; ++c){
        uint4 v;
        v.x = agg1(nb0[c].x, nb1[c].x, nb2[c].x, nb3[c].x, w0,w1,w2,w3);
        v.y = agg1(nb0[c].y, nb1[c].y, nb2[c].y, nb3[c].y, w0,w1,w2,w3);
        v.z = agg1(nb0[c].z, nb1[c].z, nb2[c].z, nb3[c].z, w0,w1,w2,w3);
        v.w = agg1(nb0[c].w, nb1[c].w, nb2[c].w, nb3[c].w, w0,w1,w2,w3);
        *(uint4*)(arow + ((qoff + (u32)c*16u) ^ sw)) = v;
      }
    }
    if (it + 1 < TPB) prefetch(it + 1);   // refill; lands during GEMM+epilogue

    __syncthreads();   // B1: agg ready

    // ---- GEMM: self (global, L2) x W0  +  agg (LDS) x W1 ----
    f32x4 acc[4][2];
#pragma unroll
    for (int m = 0; m < 4; ++m){ acc[m][0] = (f32x4){0,0,0,0}; acc[m][1] = (f32x4){0,0,0,0}; }

    const char* selfp = hb  + ((u32)(m0t + 64*wr + cB))*256u;
    const char* aggp  = agc + ((u32)(64*wr + cB))*256u;
#pragma unroll
    for (int ks = 0; ks < 4; ++ks){
      const u32 kb = (u32)ks*64u + ((u32)rg)*16u;
      const u32 kx = kb ^ kswz;
      short8 w0a = *(const short8*)(wp0 + kx);
      short8 w0b = *(const short8*)(wp1 + kx);
      short8 w1a = *(const short8*)(wp0 + 256 + kx);
      short8 w1b = *(const short8*)(wp1 + 256 + kx);
#pragma unroll
      for (int m = 0; m < 4; ++m){
        short8 s = *(const short8*)(selfp + m*4096 + kb);
        short8 a = *(const short8*)(aggp  + m*4096 + kx);
        acc[m][0] = mfma16(s, w0a, acc[m][0]);
        acc[m][1] = mfma16(s, w0b, acc[m][1]);
        acc[m][0] = mfma16(a, w1a, acc[m][0]);
        acc[m][1] = mfma16(a, w1b, acc[m][1]);
      }
    }

    // ---- LN partials (bias+relu, 16-lane shfl, cross-wave via red) ----
#pragma unroll
    for (int m = 0; m < 4; ++m){
#pragma unroll
      for (int rr = 0; rr < 4; ++rr){
        float y0 = fmaxf(acc[m][0][rr] + bj[0], 0.f);
        float y1 = fmaxf(acc[m][1][rr] + bj[1], 0.f);
        acc[m][0][rr] = y0; acc[m][1][rr] = y1;
        float s1 = y0 + y1;
        float s2 = fmaf(y0, y0, y1*y1);
        s1 += __shfl_xor(s1,1); s2 += __shfl_xor(s2,1);
        s1 += __shfl_xor(s1,2); s2 += __shfl_xor(s2,2);
        s1 += __shfl_xor(s1,4); s2 += __shfl_xor(s2,4);
        s1 += __shfl_xor(s1,8); s2 += __shfl_xor(s2,8);
        if (cB == 0) red[64*wr + 16*m + 4*rg + rr][wc] = make_float2(s1, s2);
      }
    }
    __syncthreads();   // B2: red ready (GEMM agg-reads also done)

    // ---- finalize LN + transposed pack into agc (agg consumed) ----
#pragma unroll
    for (int m = 0; m < 4; ++m){
#pragma unroll
      for (int rr = 0; rr < 4; ++rr){
        const int row = 64*wr + 16*m + 4*rg + rr;
        const float4 A = *(const float4*)&red[row][0];
        const float4 B = *(const float4*)&red[row][2];
        const float s1 = A.x + A.z + B.x + B.z;
        const float s2 = A.y + A.w + B.y + B.w;
        const float mu = s1 * (1.f/128.f);
        const float va = s2 * (1.f/128.f) - mu*mu;
        const float rs = rsqrtf(va + 1e-5f);
        const u32 sw = ((u32)(row & 7)) << 4;
        char* rowp = agc + (u32)row*256;
#pragma unroll
        for (int j = 0; j < 2; ++j){
          const float y = fmaf((acc[m][j][rr]-mu)*rs, gj[j], btj[j]);
          const float p = __shfl_xor(y, 1);
          const u32 pk = (cB & 1) ? cvtpk(p, y) : cvtpk(y, p);
          const u32 off = ((u32)(64*wc + 32*j + 2*(cB & ~1))) ^ sw;
          *(u32*)(rowp + off) = pk;
        }
      }
    }
    __syncthreads();   // B3: transpose ready

    // ---- coalesced 16B stores ----
    {
      const u32 sw2 = ((u32)(ar & 7)) << 4;
      const char* srow = agc + (u32)ar*256;
      u16* dst = hout + (size_t)(m0t + ar)*HID + aq*32;
#pragma unroll
      for (int i = 0; i < 4; ++i)
        *(short8*)(dst + i*8) = *(const short8*)(srow + ((qoff + (u32)i*16u) ^ sw2));
    }
  }
}

// Layer 1 (rank-1 shortcut): h1 = LN(relu(x*u0 + mx*u1 + c)) * g + beta
__global__ __launch_bounds__(256, 4)
void l1_k(const float* __restrict__ x, const float* __restrict__ uvec,
          const float* __restrict__ lng, const float* __restrict__ lnb,
          u16* __restrict__ hout)
{
  __shared__ float su[384];
  __shared__ float sg[128], sb[128];
  const int t = threadIdx.x;
  const int m0 = ((blockIdx.x & 7)*253 + (blockIdx.x >> 3)) * 128;
  for (int i = t; i < 384; i += 256) su[i] = uvec[i];
  if (t < 128){ sg[t] = lng[t]; sb[t] = lnb[t]; }
  __syncthreads();

  const int r = t >> 1, hf = t & 1;
  const int grow = m0 + r;
  const int nd = grow % NN;
  const int v0 = (nd >= 45), v1 = (nd <= NN-46), v2 = (nd >= 1), v3 = (nd <= NN-2);
  const int cnt = v0+v1+v2+v3;
  const float inv = (cnt==4) ? 0.25f : ((cnt==3) ? (1.f/3.f) : 0.5f);
  const float xv = x[grow];
  float mx = 0.f;
  if (v0) mx += x[grow-45];
  if (v1) mx += x[grow+45];
  if (v2) mx += x[grow-1];
  if (v3) mx += x[grow+1];
  mx *= inv;

  const int fb = hf*64;
  float4 yv[16];
  float s1 = 0.f, s2 = 0.f;
#pragma unroll
  for (int i = 0; i < 16; ++i){
    const float4 a = *(const float4*)(su + fb + i*4);
    const float4 b = *(const float4*)(su + 128 + fb + i*4);
    const float4 c = *(const float4*)(su + 256 + fb + i*4);
    float4 y;
    y.x = fmaxf(fmaf(xv, a.x, fmaf(mx, b.x, c.x)), 0.f);
    y.y = fmaxf(fmaf(xv, a.y, fmaf(mx, b.y, c.y)), 0.f);
    y.z = fmaxf(fmaf(xv, a.z, fmaf(mx, b.z, c.z)), 0.f);
    y.w = fmaxf(fmaf(xv, a.w, fmaf(mx, b.w, c.w)), 0.f);
    yv[i] = y;
    s1 += y.x + y.y + y.z + y.w;
    s2 = fmaf(y.x,y.x, fmaf(y.y,y.y, fmaf(y.z,y.z, fmaf(y.w,y.w, s2))));
  }
  s1 += __shfl_xor(s1, 1);
  s2 += __shfl_xor(s2, 1);
  const float muv = s1 * (1.f/128.f);
  const float var = s2 * (1.f/128.f) - muv*muv;
  const float rsv = rsqrtf(var + 1e-5f);

  u16* dst = hout + (size_t)grow*HID + fb;
#pragma unroll
  for (int i = 0; i < 8; ++i){
    const float4 ya = yv[2*i], yb = yv[2*i+1];
    const float4 ga = *(const float4*)(sg + fb + i*8);
    const float4 gb2 = *(const float4*)(sg + fb + i*8 + 4);
    const float4 ba = *(const float4*)(sb + fb + i*8);
    const float4 bb = *(const float4*)(sb + fb + i*8 + 4);
    u32 o0 = cvtpk(fmaf((ya.x-muv)*rsv, ga.x, ba.x), fmaf((ya.y-muv)*rsv, ga.y, ba.y));
    u32 o1 = cvtpk(fmaf((ya.z-muv)*rsv, ga.z, ba.z), fmaf((ya.w-muv)*rsv, ga.w, ba.w));
    u32 o2 = cvtpk(fmaf((yb.x-muv)*rsv, gb2.x, bb.x), fmaf((yb.y-muv)*rsv, gb2.y, bb.y));
    u32 o3 = cvtpk(fmaf((yb.z-muv)*rsv, gb2.z, bb.z), fmaf((yb.w-muv)*rsv, gb2.w, bb.w));
    uint4 pk = make_uint4(o0, o1, o2, o3);
    *(uint4*)(dst + i*8) = pk;
  }
}

// Transpose gnn_W [4][256k][128j] f32 -> Wt [4][128j][256k] bf16
__global__ void prep_k(const float* __restrict__ gw, u16* __restrict__ Wt){
  const int idx = blockIdx.x*256 + threadIdx.x;   // 131072
  const int lay = idx >> 15;
  const int r   = idx & 32767;
  const int j   = r >> 8;
  const int k   = r & 255;
  Wt[idx] = f2bf(gw[lay*32768 + k*128 + j]);
}

// u0 = We@W0_l0, u1 = We@W1_l0, c = be@(W0+W1) + b_l0
__global__ void prep2_k(const float* __restrict__ We, const float* __restrict__ be,
                        const float* __restrict__ gW, const float* __restrict__ gb,
                        float* __restrict__ uvec){
  const int f = threadIdx.x;  // 128
  float u0 = 0.f, u1 = 0.f, c = 0.f;
  for (int k = 0; k < 128; ++k){
    const float a = gW[k*128 + f];
    const float b = gW[(128+k)*128 + f];
    u0 = fmaf(We[k], a, u0);
    u1 = fmaf(We[k], b, u1);
    c  = fmaf(be[k], a + b, c);
  }
  uvec[f] = u0; uvec[128+f] = u1; uvec[256+f] = c + gb[f];
}

// stage 1 of graph mean: 8 partials per batch image
__global__ void mean1_k(const u16* __restrict__ h, float* __restrict__ partial){
  __shared__ float red[16][16][8];
  const int blk = blockIdx.x;                     // 1024 = 128 b x 8 s
  const int b = blk >> 3, s = blk & 7;
  const int t = threadIdx.x;
  const int cg = t & 15, q = t >> 4;
  const int nbeg = s*253, nend = nbeg + 253;
  float a[8] = {0.f,0.f,0.f,0.f,0.f,0.f,0.f,0.f};
  const u16* hb = h + (size_t)b * NN * HID;
  for (int n = nbeg + q; n < nend; n += 16){
    short8 v = *(const short8*)(hb + (size_t)n*HID + cg*8);
#pragma unroll
    for (int i = 0; i < 8; ++i) a[i] += bf2f((u16)v[i]);
  }
#pragma unroll
  for (int i = 0; i < 8; ++i) red[q][cg][i] = a[i];
  __syncthreads();
  if (t < 128){
    const int cc = t >> 3, i = t & 7;
    float v = 0.f;
#pragma unroll
    for (int qq = 0; qq < 16; ++qq) v += red[qq][cc][i];
    partial[((size_t)b*8 + s)*128 + t] = v;
  }
}

__global__ void mean2_k(const float* __restrict__ partial, float* __restrict__ gr){
  const int idx = blockIdx.x*256 + threadIdx.x;   // 16384
  const int b = idx >> 7, c = idx & 127;
  float a = 0.f;
#pragma unroll
  for (int s = 0; s < 8; ++s) a += partial[((size_t)b*8 + s)*128 + c];
  gr[idx] = a * (1.0f / 2024.0f);
}

__global__ void head1_k(const float* __restrict__ gr, const float* __restrict__ W1,
                        const float* __restrict__ b1, float* __restrict__ hid){
  const int idx = blockIdx.x*256 + threadIdx.x;   // 16384
  const int b = idx >> 7, j = idx & 127;
  const float* g = gr + b*128;
  float a = b1[j];
  for (int k = 0; k < 128; ++k) a = fmaf(g[k], W1[k*128 + j], a);
  hid[idx] = fmaxf(a, 0.f);
}

__global__ void head2_k(const float* __restrict__ hid, const float* __restrict__ W2,
                        const float* __restrict__ b2, float* __restrict__ out){
  const int t = threadIdx.x;                      // 256 = 128 b x 2 o
  const int b = t >> 1, o = t & 1;
  const float* hh = hid + b*128;
  float a = b2[o];
  for (int k = 0; k < 128; ++k) a = fmaf(hh[k], W2[k*2 + o], a);
  out[t] = a;
}

extern "C" void kernel_launch(void* const* d_in, const int* in_sizes, int n_in,
                              void* d_out, int out_size, void* d_ws, size_t ws_size,
                              hipStream_t stream){
  const float* x  = (const float*)d_in[0];
  const float* We = (const float*)d_in[1];
  const float* be = (const float*)d_in[2];
  const float* gW = (const float*)d_in[3];
  const float* gb = (const float*)d_in[4];
  const float* lg = (const float*)d_in[5];
  const float* lb = (const float*)d_in[6];
  const float* W1 = (const float*)d_in[7];
  const float* b1 = (const float*)d_in[8];
  const float* W2 = (const float*)d_in[9];
  const float* b2 = (const float*)d_in[10];
  float* out = (float*)d_out;

  char* w = (char*)d_ws;
  const size_t HB = (size_t)MTOT * HID * 2;       // 66,322,432 B per h buffer
  u16*   hA   = (u16*)w;
  u16*   hB   = (u16*)(w + HB);
  u16*   Wt   = (u16*)(w + 2*HB);                 // 262,144 B
  float* gr   = (float*)(w + 2*HB + 262144);      // 65,536 B
  float* hid  = (float*)(w + 2*HB + 262144 + 65536);
  float* uvec = (float*)(w + 2*HB + 262144 + 131072);
  float* partial = (float*)w;                     // overlays hA (dead after layer 3)

  prep2_k<<<1, 128, 0, stream>>>(We, be, gW, gb, uvec);
  prep_k<<<512, 256, 0, stream>>>(gW, Wt);
  l1_k<<<MTOT/128, 256, 0, stream>>>(x, uvec, lg, lb, hA);
  layerP_k<<<NPBLK, 512, 0, stream>>>(hA, Wt + 32768, gb + 128, lg + 128, lb + 128, hB);
  layerP_k<<<NPBLK, 512, 0, stream>>>(hB, Wt + 65536, gb + 256, lg + 256, lb + 256, hA);
  layerP_k<<<NPBLK, 512, 0, stream>>>(hA, Wt + 98304, gb + 384, lg + 384, lb + 384, hB);
  mean1_k<<<NB*8, 256, 0, stream>>>(hB, partial);
  mean2_k<<<64, 256, 0, stream>>>(partial, gr);
  head1_k<<<64, 256, 0, stream>>>(gr, W1, b1, hid);
  head2_k<<<1, 256, 0, stream>>>(hid, W2, b2, out);
}